// Round 5
// baseline (297.643 us; speedup 1.0000x reference)
//
#include <hip/hip_runtime.h>
#include <hip/hip_bf16.h>

typedef unsigned short u16;
typedef __attribute__((ext_vector_type(8))) __bf16 bf16x8;
typedef __attribute__((ext_vector_type(4))) float f32x4;

#define AS1 __attribute__((address_space(1)))
#define AS3 __attribute__((address_space(3)))

__device__ __forceinline__ u16 f2bf(float f) {
    union { float f; unsigned u; } v; v.f = f;
    unsigned u = v.u;
    return (u16)((u + 0x7FFFu + ((u >> 16) & 1u)) >> 16);   // RTNE
}

// ---- fused fp32 -> bf16 convert for all 4 tensors (grid-stride) ------------
__global__ void cvt4(const float4* __restrict__ a, const float4* __restrict__ b,
                     const float4* __restrict__ c, const float4* __restrict__ d,
                     ushort4* __restrict__ oa, ushort4* __restrict__ ob,
                     ushort4* __restrict__ oc, ushort4* __restrict__ od,
                     int na, int nb, int nc, int nd) {
    const int total = na + nb + nc + nd;
    for (int i = blockIdx.x * blockDim.x + threadIdx.x; i < total;
         i += gridDim.x * blockDim.x) {
        const float4* s; ushort4* o; int j = i;
        if (j < na) { s = a; o = oa; }
        else {
            j -= na;
            if (j < nb) { s = b; o = ob; }
            else {
                j -= nb;
                if (j < nc) { s = c; o = oc; }
                else        { j -= nc; s = d; o = od; }
            }
        }
        float4 v = s[j];
        ushort4 u;
        u.x = f2bf(v.x); u.y = f2bf(v.y); u.z = f2bf(v.z); u.w = f2bf(v.w);
        o[j] = u;
    }
}

// ---- bf16 NT GEMM: BM=256, BN=128, BK=64, 8 waves (4M x 2N), 64x64/wave ----
// Triple-buffered LDS, stage t+2 during iter t, counted vmcnt(6) once/tile.
// T3: each K-tile split into 4 quadrant phases:
//   {ds_read subtile ∥ stage-issue → barrier → lgkmcnt(0) → setprio(1)
//    → 8 MFMA → setprio(0) → barrier}
// Swizzle (T2, verified 0 conflicts): logical 16B chunk cl stored at physical
// cl ^ (row&7); linear gload_lds dest + inverse-swizzled global src + swizzled
// ds_read (rule #21).
template<int MODE>
__global__ __launch_bounds__(512, 2)
void gemm_bt(const u16* __restrict__ A0, const u16* __restrict__ A1,
             const u16* __restrict__ Bm, const float* __restrict__ bias,
             float* __restrict__ Cf, u16* __restrict__ Cbf,
             int M, int N, int K)
{
    extern __shared__ u16 lds[];
    const int tid  = threadIdx.x;
    const int wave = tid >> 6;
    const int lane = tid & 63;

    const int nN  = N >> 7;                 // tiles along N (BN=128)
    const int nwg = (M >> 8) * nN;          // total tiles (BM=256)
    const int id  = ((int)blockIdx.x % 8) * (nwg >> 3) + (int)blockIdx.x / 8;  // T1
    const int m0  = (id / nN) << 8;
    const int n0  = (id % nN) << 7;

    const int fr = lane & 15, fq = lane >> 4;
    const int wr = wave >> 1, wc = wave & 1;

    const int srow   = tid >> 3;                       // staging row in 64-row round
    const int schunk = (tid & 7) ^ (srow & 7);         // inverse-swizzled src chunk
    const int ldsW   = wave << 9;                      // wave*512 u16 dest base

    f32x4 acc[4][4];
    #pragma unroll
    for (int i = 0; i < 4; ++i)
        #pragma unroll
        for (int j = 0; j < 4; ++j)
            acc[i][j] = f32x4{0.f, 0.f, 0.f, 0.f};

    const int lda = (MODE == 0) ? 2048 : K;

    // part 0: A rows 0-127 (rounds 0,1); part 1: A rows 128-255 (rounds 2,3);
    // part 2: B rows 0-127 (rounds 0,1). 2 gload_lds each.
    auto stage_part = [&](int t, int part) {
        const int k0  = t << 6;
        const int buf = (t % 3) * 24576;
        if (part < 2) {
            const u16* As; int kc;
            if constexpr (MODE == 0) { As = (k0 < 2048) ? A0 : A1; kc = k0 & 2047; }
            else                     { As = A0;                    kc = k0;        }
            #pragma unroll
            for (int rr = 0; rr < 2; ++rr) {
                const int r = part * 2 + rr;
                const u16* g = As + (size_t)(m0 + (r << 6) + srow) * lda + kc + (schunk << 3);
                __builtin_amdgcn_global_load_lds((const AS1 unsigned int*)g,
                    (AS3 unsigned int*)&lds[buf + (r << 12) + ldsW], 16, 0, 0);
            }
        } else {
            #pragma unroll
            for (int r = 0; r < 2; ++r) {
                const u16* g = Bm + (size_t)(n0 + (r << 6) + srow) * K + k0 + (schunk << 3);
                __builtin_amdgcn_global_load_lds((const AS1 unsigned int*)g,
                    (AS3 unsigned int*)&lds[buf + 16384 + (r << 12) + ldsW], 16, 0, 0);
            }
        }
    };

    // read-side swizzled chunk offsets (row&7 == fr&7 for all our rows)
    const int ax0 = ((fq)     ^ (fr & 7)) << 3;   // ksub 0: logical chunk fq
    const int ax1 = ((4 + fq) ^ (fr & 7)) << 3;   // ksub 1: logical chunk 4+fq
    const int aoff = ((wr << 6) + fr) << 6;       // row*64 u16
    const int boff = ((wc << 6) + fr) << 6;

    const int nt = K >> 6;

    // prologue: stage tiles 0,1 fully; wait tile 0 (tile 1's 6 may remain)
    stage_part(0, 0); stage_part(0, 1); stage_part(0, 2);
    stage_part(1, 0); stage_part(1, 1); stage_part(1, 2);
    asm volatile("s_waitcnt vmcnt(6)" ::: "memory");
    __builtin_amdgcn_s_barrier();

    for (int t = 0; t < nt; ++t) {
        const int buf = (t % 3) * 24576;
        const bool pf = (t + 2 < nt);

        bf16x8 aL[2][2], aH[2][2], bL[2][2], bH[2][2];   // [frag][ksub]

        // ---- phase 1: read A-low + B-low; stage part 0; MFMA q(lo,lo)
        #pragma unroll
        for (int i = 0; i < 2; ++i) {
            aL[i][0] = *(const bf16x8*)&lds[buf + aoff + (i << 10) + ax0];
            aL[i][1] = *(const bf16x8*)&lds[buf + aoff + (i << 10) + ax1];
            bL[i][0] = *(const bf16x8*)&lds[buf + 16384 + boff + (i << 10) + ax0];
            bL[i][1] = *(const bf16x8*)&lds[buf + 16384 + boff + (i << 10) + ax1];
        }
        if (pf) stage_part(t + 2, 0);
        __builtin_amdgcn_s_barrier();
        asm volatile("s_waitcnt lgkmcnt(0)" ::: "memory");
        __builtin_amdgcn_s_setprio(1);
        #pragma unroll
        for (int i = 0; i < 2; ++i)
            #pragma unroll
            for (int j = 0; j < 2; ++j) {
                acc[i][j] = __builtin_amdgcn_mfma_f32_16x16x32_bf16(aL[i][0], bL[j][0], acc[i][j], 0, 0, 0);
                acc[i][j] = __builtin_amdgcn_mfma_f32_16x16x32_bf16(aL[i][1], bL[j][1], acc[i][j], 0, 0, 0);
            }
        __builtin_amdgcn_s_setprio(0);
        __builtin_amdgcn_s_barrier();

        // ---- phase 2: read B-high; stage part 1; MFMA q(lo,hi) (reuse aL)
        #pragma unroll
        for (int j = 0; j < 2; ++j) {
            bH[j][0] = *(const bf16x8*)&lds[buf + 16384 + boff + ((j + 2) << 10) + ax0];
            bH[j][1] = *(const bf16x8*)&lds[buf + 16384 + boff + ((j + 2) << 10) + ax1];
        }
        if (pf) stage_part(t + 2, 1);
        __builtin_amdgcn_s_barrier();
        asm volatile("s_waitcnt lgkmcnt(0)" ::: "memory");
        __builtin_amdgcn_s_setprio(1);
        #pragma unroll
        for (int i = 0; i < 2; ++i)
            #pragma unroll
            for (int j = 0; j < 2; ++j) {
                acc[i][j + 2] = __builtin_amdgcn_mfma_f32_16x16x32_bf16(aL[i][0], bH[j][0], acc[i][j + 2], 0, 0, 0);
                acc[i][j + 2] = __builtin_amdgcn_mfma_f32_16x16x32_bf16(aL[i][1], bH[j][1], acc[i][j + 2], 0, 0, 0);
            }
        __builtin_amdgcn_s_setprio(0);
        __builtin_amdgcn_s_barrier();

        // ---- phase 3: read A-high; MFMA q(hi,lo)
        #pragma unroll
        for (int i = 0; i < 2; ++i) {
            aH[i][0] = *(const bf16x8*)&lds[buf + aoff + ((i + 2) << 10) + ax0];
            aH[i][1] = *(const bf16x8*)&lds[buf + aoff + ((i + 2) << 10) + ax1];
        }
        __builtin_amdgcn_s_barrier();
        asm volatile("s_waitcnt lgkmcnt(0)" ::: "memory");
        __builtin_amdgcn_s_setprio(1);
        #pragma unroll
        for (int i = 0; i < 2; ++i)
            #pragma unroll
            for (int j = 0; j < 2; ++j) {
                acc[i + 2][j] = __builtin_amdgcn_mfma_f32_16x16x32_bf16(aH[i][0], bL[j][0], acc[i + 2][j], 0, 0, 0);
                acc[i + 2][j] = __builtin_amdgcn_mfma_f32_16x16x32_bf16(aH[i][1], bL[j][1], acc[i + 2][j], 0, 0, 0);
            }
        __builtin_amdgcn_s_setprio(0);
        __builtin_amdgcn_s_barrier();

        // ---- phase 4: stage part 2; MFMA q(hi,hi); end-of-iter counted wait
        if (pf) stage_part(t + 2, 2);
        __builtin_amdgcn_s_setprio(1);
        #pragma unroll
        for (int i = 0; i < 2; ++i)
            #pragma unroll
            for (int j = 0; j < 2; ++j) {
                acc[i + 2][j + 2] = __builtin_amdgcn_mfma_f32_16x16x32_bf16(aH[i][0], bH[j][0], acc[i + 2][j + 2], 0, 0, 0);
                acc[i + 2][j + 2] = __builtin_amdgcn_mfma_f32_16x16x32_bf16(aH[i][1], bH[j][1], acc[i + 2][j + 2], 0, 0, 0);
            }
        __builtin_amdgcn_s_setprio(0);

        if (t + 1 < nt) {
            // counted: tile t+2's 6 loads may stay in flight; tile t+1 landed.
            if (pf) asm volatile("s_waitcnt vmcnt(6)" ::: "memory");
            else    asm volatile("s_waitcnt vmcnt(0)" ::: "memory");
            __builtin_amdgcn_s_barrier();
        }
    }

    // epilogue: C/D layout col = lane&15, row = (lane>>4)*4 + reg
    #pragma unroll
    for (int j = 0; j < 4; ++j) {
        const int col = n0 + (wc << 6) + (j << 4) + fr;
        const float bv = bias[col];
        #pragma unroll
        for (int i = 0; i < 4; ++i) {
            #pragma unroll
            for (int r = 0; r < 4; ++r) {
                const int row = m0 + (wr << 6) + (i << 4) + (fq << 2) + r;
                float v = acc[i][j][r] + bv;
                if constexpr (MODE == 0) {
                    v = tanhf(v);
                    Cf[(size_t)row * N + col]  = v;
                    Cbf[(size_t)row * N + col] = f2bf(v);
                } else {
                    Cf[(size_t)row * N + col] = v;
                }
            }
        }
    }
}

extern "C" void kernel_launch(void* const* d_in, const int* in_sizes, int n_in,
                              void* d_out, int out_size, void* d_ws, size_t ws_size,
                              hipStream_t stream) {
    const float* x   = (const float*)d_in[0];   // [B, I]
    const float* hid = (const float*)d_in[1];   // [B, H]
    const float* Wih = (const float*)d_in[2];   // [H, I+H]
    const float* bih = (const float*)d_in[3];   // [H]
    const float* Who = (const float*)d_in[4];   // [O, H]
    const float* bho = (const float*)d_in[5];   // [O]
    float* out = (float*)d_out;

    const int B = 4096, I = 2048, H = 2048, O = 2048;

    u16* x_bf   = (u16*)d_ws;                     // B*I
    u16* h_bf   = x_bf   + (size_t)B * I;         // B*H
    u16* wih_bf = h_bf   + (size_t)B * H;         // H*(I+H)
    u16* who_bf = wih_bf + (size_t)H * (I + H);   // O*H
    u16* nh_bf  = who_bf + (size_t)O * H;         // B*H

    const int na = (B * I) / 4, nb = (B * H) / 4,
              nc = (H * (I + H)) / 4, nd = (O * H) / 4;
    cvt4<<<dim3(2048), dim3(256), 0, stream>>>(
        (const float4*)x, (const float4*)hid, (const float4*)Wih, (const float4*)Who,
        (ushort4*)x_bf, (ushort4*)h_bf, (ushort4*)wih_bf, (ushort4*)who_bf,
        na, nb, nc, nd);

    float* out_y  = out;                    // [B, O]
    float* out_nh = out + (size_t)B * O;    // [B, H]

    const size_t shmem = 3 * 24576 * sizeof(u16);   // 147456 B
    hipFuncSetAttribute(reinterpret_cast<const void*>(&gemm_bt<0>),
                        hipFuncAttributeMaxDynamicSharedMemorySize, (int)shmem);
    hipFuncSetAttribute(reinterpret_cast<const void*>(&gemm_bt<1>),
                        hipFuncAttributeMaxDynamicSharedMemorySize, (int)shmem);

    // GEMM1: new_hidden = tanh([x,hid] @ W_ih^T + b_ih)   M=4096,N=2048,K=4096
    gemm_bt<0><<<dim3((B / 256) * (H / 128)), dim3(512), shmem, stream>>>(
        x_bf, h_bf, wih_bf, bih, out_nh, nh_bf, B, H, I + H);

    // GEMM2: output = new_hidden @ W_ho^T + b_ho          M=4096,N=2048,K=2048
    gemm_bt<1><<<dim3((B / 256) * (O / 128)), dim3(512), shmem, stream>>>(
        nh_bf, nh_bf, who_bf, bho, out_y, nullptr, B, O, H);
}

// Round 7
// 286.598 us; speedup vs baseline: 1.0385x; 1.0385x over previous
//
#include <hip/hip_runtime.h>
#include <hip/hip_bf16.h>

typedef unsigned short u16;
typedef __attribute__((ext_vector_type(8))) __bf16 bf16x8;
typedef __attribute__((ext_vector_type(4))) float f32x4;

#define AS1 __attribute__((address_space(1)))
#define AS3 __attribute__((address_space(3)))

__device__ __forceinline__ u16 f2bf(float f) {
    union { float f; unsigned u; } v; v.f = f;
    unsigned u = v.u;
    return (u16)((u + 0x7FFFu + ((u >> 16) & 1u)) >> 16);   // RTNE
}

// ---- dedicated fp32 -> bf16 converts (exact grid, branch-free) -------------
__global__ void cvt_plain(const float4* __restrict__ src,
                          ushort4* __restrict__ dst, int n4) {
    int i = blockIdx.x * blockDim.x + threadIdx.x;
    if (i < n4) {
        float4 v = src[i];
        ushort4 u;
        u.x = f2bf(v.x); u.y = f2bf(v.y); u.z = f2bf(v.z); u.w = f2bf(v.w);
        dst[i] = u;
    }
}

// x / hidden -> combined[4096][4096] halves. src is [4096][2048] f32
// (512 float4/row); dst row stride = 1024 ushort4. Pass dst offset by +512
// ushort4 for the hidden half.
__global__ void cvt_half(const float4* __restrict__ src,
                         ushort4* __restrict__ dst, int n4) {
    int i = blockIdx.x * blockDim.x + threadIdx.x;
    if (i < n4) {
        float4 v = src[i];
        ushort4 u;
        u.x = f2bf(v.x); u.y = f2bf(v.y); u.z = f2bf(v.z); u.w = f2bf(v.w);
        dst[((i >> 9) << 10) + (i & 511)] = u;
    }
}

// ---- bf16 NT GEMM: BM=256, BN=128, BK=64, 8 waves (4M x 2N), 64x64/wave ----
// Round-3 proven structure: monolithic K-loop, triple-buffered LDS,
// stage t+2 during iter t, ONE barrier + counted vmcnt(6) per K-tile.
// A-stride == K for both GEMMs (combined layout). Staging addresses are
// induction pointers (+64 u16 per staged tile).
// T2 swizzle (verified 0 conflicts): logical 16B chunk cl at physical
// cl ^ (row&7); linear gload_lds dest + inverse-swizzled global src +
// swizzled ds_read (rule #21).
template<int MODE>
__global__ __launch_bounds__(512, 2)
void gemm_bt(const u16* __restrict__ A, const u16* __restrict__ Bm,
             const float* __restrict__ bias,
             float* __restrict__ Cf, u16* __restrict__ Cbf,
             int M, int N, int K)
{
    extern __shared__ u16 lds[];
    const int tid  = threadIdx.x;
    const int wave = tid >> 6;
    const int lane = tid & 63;

    const int nN  = N >> 7;                 // tiles along N (BN=128)
    const int nwg = (M >> 8) * nN;          // total tiles (BM=256)
    const int id  = ((int)blockIdx.x % 8) * (nwg >> 3) + (int)blockIdx.x / 8;  // T1
    const int m0  = (id / nN) << 8;
    const int n0  = (id % nN) << 7;

    const int fr = lane & 15, fq = lane >> 4;
    const int wr = wave >> 1, wc = wave & 1;

    const int srow   = tid >> 3;                       // staging row in 64-row round
    const int schunk = (tid & 7) ^ (srow & 7);         // inverse-swizzled src chunk
    const int ldsW   = wave << 9;                      // wave*512 u16 dest base

    f32x4 acc[4][4];
    #pragma unroll
    for (int i = 0; i < 4; ++i)
        #pragma unroll
        for (int j = 0; j < 4; ++j)
            acc[i][j] = f32x4{0.f, 0.f, 0.f, 0.f};

    // induction pointers for the 6 staging loads (advance 64 u16 per tile)
    const u16* pa[4];
    const u16* pb[2];
    #pragma unroll
    for (int r = 0; r < 4; ++r)
        pa[r] = A + (size_t)(m0 + (r << 6) + srow) * K + (schunk << 3);
    #pragma unroll
    for (int r = 0; r < 2; ++r)
        pb[r] = Bm + (size_t)(n0 + (r << 6) + srow) * K + (schunk << 3);

    int sbuf = 0;   // LDS buffer offset (u16 units) for the NEXT stage call
    auto stage = [&]() {
        #pragma unroll
        for (int r = 0; r < 4; ++r) {
            __builtin_amdgcn_global_load_lds((const AS1 unsigned int*)pa[r],
                (AS3 unsigned int*)&lds[sbuf + (r << 12) + ldsW], 16, 0, 0);
            pa[r] += 64;
        }
        #pragma unroll
        for (int r = 0; r < 2; ++r) {
            __builtin_amdgcn_global_load_lds((const AS1 unsigned int*)pb[r],
                (AS3 unsigned int*)&lds[sbuf + 16384 + (r << 12) + ldsW], 16, 0, 0);
            pb[r] += 64;
        }
        sbuf = (sbuf == 49152) ? 0 : sbuf + 24576;
    };

    // read-side swizzled chunk offsets (row&7 == fr&7 for all our rows)
    const int ax0 = ((fq)     ^ (fr & 7)) << 3;   // ksub 0: logical chunk fq
    const int ax1 = ((4 + fq) ^ (fr & 7)) << 3;   // ksub 1: logical chunk 4+fq
    const int aoff = ((wr << 6) + fr) << 6;       // row*64 u16
    const int boff = ((wc << 6) + fr) << 6;

    const int nt = K >> 6;

    // prologue: stage tiles 0,1; wait tile 0 (tile 1's 6 loads may remain)
    stage(); stage();
    asm volatile("s_waitcnt vmcnt(6)" ::: "memory");
    __builtin_amdgcn_s_barrier();

    int rbuf = 0;   // LDS buffer offset being computed this iter
    for (int t = 0; t < nt; ++t) {
        const bool pf = (t + 2 < nt);
        if (pf) stage();   // into buf[(t+2)%3] == buf[(t-1)%3], already consumed

        bf16x8 a0[4], a1[4], b0[4], b1[4];
        #pragma unroll
        for (int i = 0; i < 4; ++i) {
            a0[i] = *(const bf16x8*)&lds[rbuf + aoff + (i << 10) + ax0];
            a1[i] = *(const bf16x8*)&lds[rbuf + aoff + (i << 10) + ax1];
        }
        #pragma unroll
        for (int j = 0; j < 4; ++j) {
            b0[j] = *(const bf16x8*)&lds[rbuf + 16384 + boff + (j << 10) + ax0];
            b1[j] = *(const bf16x8*)&lds[rbuf + 16384 + boff + (j << 10) + ax1];
        }

        __builtin_amdgcn_s_setprio(1);
        #pragma unroll
        for (int i = 0; i < 4; ++i)
            #pragma unroll
            for (int j = 0; j < 4; ++j) {
                acc[i][j] = __builtin_amdgcn_mfma_f32_16x16x32_bf16(a0[i], b0[j], acc[i][j], 0, 0, 0);
                acc[i][j] = __builtin_amdgcn_mfma_f32_16x16x32_bf16(a1[i], b1[j], acc[i][j], 0, 0, 0);
            }
        __builtin_amdgcn_s_setprio(0);

        if (t + 1 < nt) {
            // counted: tile t+2's 6 loads may stay in flight; tile t+1 landed.
            if (pf) asm volatile("s_waitcnt vmcnt(6)" ::: "memory");
            else    asm volatile("s_waitcnt vmcnt(0)" ::: "memory");
            __builtin_amdgcn_s_barrier();
        }
        rbuf = (rbuf == 49152) ? 0 : rbuf + 24576;
    }

    // epilogue: C/D layout col = lane&15, row = (lane>>4)*4 + reg
    #pragma unroll
    for (int j = 0; j < 4; ++j) {
        const int col = n0 + (wc << 6) + (j << 4) + fr;
        const float bv = bias[col];
        #pragma unroll
        for (int i = 0; i < 4; ++i) {
            #pragma unroll
            for (int r = 0; r < 4; ++r) {
                const int row = m0 + (wr << 6) + (i << 4) + (fq << 2) + r;
                float v = acc[i][j][r] + bv;
                if constexpr (MODE == 0) {
                    v = tanhf(v);
                    Cf[(size_t)row * N + col]  = v;
                    Cbf[(size_t)row * N + col] = f2bf(v);
                } else {
                    Cf[(size_t)row * N + col] = v;
                }
            }
        }
    }
}

extern "C" void kernel_launch(void* const* d_in, const int* in_sizes, int n_in,
                              void* d_out, int out_size, void* d_ws, size_t ws_size,
                              hipStream_t stream) {
    const float* x   = (const float*)d_in[0];   // [B, I]
    const float* hid = (const float*)d_in[1];   // [B, H]
    const float* Wih = (const float*)d_in[2];   // [H, I+H]
    const float* bih = (const float*)d_in[3];   // [H]
    const float* Who = (const float*)d_in[4];   // [O, H]
    const float* bho = (const float*)d_in[5];   // [O]
    float* out = (float*)d_out;

    const int B = 4096, I = 2048, H = 2048, O = 2048;

    // workspace (bf16): combined [B][I+H] 32MB, W_ih 16MB, W_ho 8MB, nh 16MB
    u16* comb   = (u16*)d_ws;                     // B*(I+H)
    u16* wih_bf = comb   + (size_t)B * (I + H);   // H*(I+H)
    u16* who_bf = wih_bf + (size_t)H * (I + H);   // O*H
    u16* nh_bf  = who_bf + (size_t)O * H;         // B*H

    // converts: x/hid into combined halves; weights plain
    {
        const int n4x = (B * I) / 4;              // 2M float4
        cvt_half<<<dim3((n4x + 255) / 256), dim3(256), 0, stream>>>(
            (const float4*)x, (ushort4*)comb, n4x);
        cvt_half<<<dim3((n4x + 255) / 256), dim3(256), 0, stream>>>(
            (const float4*)hid, (ushort4*)comb + 512, n4x);
        const int n4w = (H * (I + H)) / 4;
        cvt_plain<<<dim3((n4w + 255) / 256), dim3(256), 0, stream>>>(
            (const float4*)Wih, (ushort4*)wih_bf, n4w);
        const int n4o = (O * H) / 4;
        cvt_plain<<<dim3((n4o + 255) / 256), dim3(256), 0, stream>>>(
            (const float4*)Who, (ushort4*)who_bf, n4o);
    }

    float* out_y  = out;                    // [B, O]
    float* out_nh = out + (size_t)B * O;    // [B, H]

    const size_t shmem = 3 * 24576 * sizeof(u16);   // 147456 B
    hipFuncSetAttribute(reinterpret_cast<const void*>(&gemm_bt<0>),
                        hipFuncAttributeMaxDynamicSharedMemorySize, (int)shmem);
    hipFuncSetAttribute(reinterpret_cast<const void*>(&gemm_bt<1>),
                        hipFuncAttributeMaxDynamicSharedMemorySize, (int)shmem);

    // GEMM1: new_hidden = tanh(combined @ W_ih^T + b_ih)  M=4096,N=2048,K=4096
    gemm_bt<0><<<dim3((B / 256) * (H / 128)), dim3(512), shmem, stream>>>(
        comb, wih_bf, bih, out_nh, nh_bf, B, H, I + H);

    // GEMM2: output = new_hidden @ W_ho^T + b_ho          M=4096,N=2048,K=2048
    gemm_bt<1><<<dim3((B / 256) * (O / 128)), dim3(512), shmem, stream>>>(
        nh_bf, who_bf, bho, out_y, nullptr, B, O, H);
}